// Round 8
// baseline (367.901 us; speedup 1.0000x reference)
//
#include <hip/hip_runtime.h>
#include <hip/hip_fp16.h>

#define N_NODES 100000
#define N_EDGES 3200000
#define BATCH   16
#define HIDDEN  64

#define NBINS   512
#define NPB     196      /* nodes per bin; 512*196 = 100352 >= N_NODES */
#define NSH     8        /* gcnt shards per bin (pblk & 7): 391/8 ~ 49 contenders */
#define CAP_SH  1024     /* words per shard region; mean 800, sigma 28 -> +8 sigma */
#define CAP_BIN 8192     /* NSH * CAP_SH */
#define EPB     8192     /* 16 edges/thread x 512 thr; 391 partition blocks */
#define ACCW    17       /* padded accumulator row stride (bank spread) */

#define PBLKS   391      /* partition blocks: 391*8192 >= 3.2M */
#define TBLKS   196      /* transpose blocks (512 thr): 196*512 >= 100000 */
#define LBLKS   17       /* lut blocks (512 thr): 17*512 >= 8193 */

#define LUT_SIZE  8192
#define LUT_LO    (-16.0f)
#define LUT_SCALE (LUT_SIZE / 32.0f)

typedef int v4i __attribute__((ext_vector_type(4)));

// ---------------------------------------------------------------------------
// Kernel 1 — EXACT round-5 winner (124.4us config; round-7's fold regressed:
// in-block transpose serializes onto the partition critical path instead of
// running as concurrent cheap blocks). Transpose+LUT blocks first
// (ids 0..212), partition blocks after (ids 213..603).
// Partition: radix by dest bin (r/NPB), LDS atomic histogram+rank, shfl
// scan, place at prefix+rank, coalesced run copy-out; global reservation
// sharded 8 ways (round-2). Plain stores (round-3: L2 write-combines).
// gcnt is zeroed by hipMemsetAsync before this kernel.
// Packed word: (r_local << 17) | c  (8 + 17 = 25 bits).
// ---------------------------------------------------------------------------
__global__ __launch_bounds__(512) void fused_part_prep_kernel(
    const int* __restrict__ ei, unsigned int* __restrict__ gcnt,
    unsigned int* __restrict__ packed,
    const float* __restrict__ mu, __half* __restrict__ mu_h,
    const float* __restrict__ W1, const float* __restrict__ b1,
    const float* __restrict__ W2, const float* __restrict__ b2,
    float* __restrict__ lut) {
  __shared__ int aux[NBINS];               // 2 KB: cnt -> prefix
  __shared__ int dlt[NBINS];               // 2 KB: delta = shard base - prefix
  __shared__ int wsum[8];
  __shared__ unsigned int stag[EPB];       // 32 KB
  __shared__ unsigned short sbin[EPB];     // 16 KB

  int blk = blockIdx.x;
  int t = threadIdx.x;

  if (blk < TBLKS + LBLKS) {
    if (blk < TBLKS) {
      // ---- transpose (runs concurrently with partition blocks) ----
      int n = blk * 512 + t;
      if (n >= N_NODES) return;
      float4 o[4];
#pragma unroll
      for (int q = 0; q < 4; ++q) {
        o[q].x = mu[(q * 4 + 0) * N_NODES + n];
        o[q].y = mu[(q * 4 + 1) * N_NODES + n];
        o[q].z = mu[(q * 4 + 2) * N_NODES + n];
        o[q].w = mu[(q * 4 + 3) * N_NODES + n];
      }
      __half2 hh[8];
#pragma unroll
      for (int q = 0; q < 4; ++q) {
        hh[2 * q]     = __floats2half2_rn(o[q].x, o[q].y);
        hh[2 * q + 1] = __floats2half2_rn(o[q].z, o[q].w);
      }
      int4 w0 = make_int4(*(int*)&hh[0], *(int*)&hh[1], *(int*)&hh[2], *(int*)&hh[3]);
      int4 w1 = make_int4(*(int*)&hh[4], *(int*)&hh[5], *(int*)&hh[6], *(int*)&hh[7]);
      int4* dst = (int4*)(mu_h + (size_t)n * BATCH);
      dst[0] = w0;
      dst[1] = w1;
    } else {
      // ---- LUT ----
      int i = (blk - TBLKS) * 512 + t;
      if (i > LUT_SIZE) return;
      float x = LUT_LO + (float)i / LUT_SCALE;
      float acc = b2[0];
      for (int h = 0; h < HIDDEN; ++h) {
        float z = fmaf(x, W1[h], b1[h]);
        float g = 0.5f * z * (1.0f + erff(z * 0.70710678118654752f));
        acc = fmaf(g, W2[h], acc);
      }
      lut[i] = acc;
    }
    return;
  }

  // ---- partition ----
  int pblk = blk - (TBLKS + LBLKS);
  int base = pblk * EPB;
  int nvalid = min(EPB, N_EDGES - base);
  int sh = pblk & (NSH - 1);
  aux[t] = 0;
  __syncthreads();

  unsigned int pk[16];
  int bn[16];
  int rk[16];
  if (t * 16 + 16 <= nvalid) {
    const v4i* rp = (const v4i*)(ei + base + t * 16);          // 64B aligned
    const v4i* cp = (const v4i*)(ei + N_EDGES + base + t * 16);
    v4i rr[4], cc[4];
#pragma unroll
    for (int q = 0; q < 4; ++q) {
      rr[q] = rp[q];
      cc[q] = cp[q];
    }
#pragma unroll
    for (int q = 0; q < 4; ++q) {
#pragma unroll
      for (int u = 0; u < 4; ++u) {
        int k = q * 4 + u;
        int r = rr[q][u];
        int c = cc[q][u];
        int b = r / NPB;                    // magic-mul
        int rl = r - b * NPB;
        pk[k] = ((unsigned int)rl << 17) | (unsigned int)c;
        bn[k] = b;
      }
    }
#pragma unroll
    for (int k = 0; k < 16; ++k) rk[k] = atomicAdd(&aux[bn[k]], 1);
  } else {
#pragma unroll
    for (int k = 0; k < 16; ++k) {
      int e = t * 16 + k;
      if (e < nvalid) {
        int r = ei[base + e];
        int c = ei[N_EDGES + base + e];
        int b = r / NPB;
        int rl = r - b * NPB;
        pk[k] = ((unsigned int)rl << 17) | (unsigned int)c;
        bn[k] = b;
        rk[k] = atomicAdd(&aux[b], 1);
      } else {
        bn[k] = -1;
      }
    }
  }
  __syncthreads();

  // shfl scan over 512 bins (one per thread); aux: cnt -> prefix
  int lane = t & 63;
  int wid = t >> 6;
  int v = aux[t];

  // reserve sharded global space early (latency hidden behind scan);
  // per-address contention ~49 blocks instead of 391
  unsigned int gb = v ? atomicAdd(&gcnt[t * NSH + sh], (unsigned int)v) : 0u;

  int sv = v;
#pragma unroll
  for (int d = 1; d < 64; d <<= 1) {
    int n = __shfl_up(sv, d, 64);
    if (lane >= d) sv += n;
  }
  if (lane == 63) wsum[wid] = sv;
  __syncthreads();
  if (t < 8) {
    int s = wsum[t];
#pragma unroll
    for (int d = 1; d < 8; d <<= 1) {
      int n = __shfl_up(s, d, 8);
      if (t >= d) s += n;
    }
    wsum[t] = s;
  }
  __syncthreads();
  int pexcl = sv + (wid ? wsum[wid - 1] : 0) - v;
  aux[t] = pexcl;                              // prefix for the place pass
  dlt[t] = (int)(sh * CAP_SH + gb) - pexcl;    // delta for the copy-out pass
  __syncthreads();

  // place at prefix+rank (no atomics)
#pragma unroll
  for (int k = 0; k < 16; ++k) {
    if (bn[k] >= 0) {
      int p = aux[bn[k]] + rk[k];
      stag[p] = pk[k];
      sbin[p] = (unsigned short)bn[k];
    }
  }
  __syncthreads();

  // coalesced copy-out: pos = i + delta[bin]; drop past own shard region.
  // Plain stores: write-combine in L2, full-line writeback at kernel end.
  unsigned int lim = (unsigned int)((sh + 1) * CAP_SH);
  for (int i = t; i < nvalid; i += 512) {
    int b = sbin[i];
    unsigned int pos = (unsigned int)(i + dlt[b]);
    if (pos < lim)
      packed[(size_t)b * CAP_BIN + pos] = stag[i];
  }
}

// ---------------------------------------------------------------------------
// Kernel 2 — ROUND 8 REWRITE: direct LDS fp32 accumulation replaces
// sort-then-sum. Old structure spent 4 barriers + 8192 rank atomics + scan
// + scattered place + serial variable-length per-node gather, all to make
// register accumulation possible. New: (1) compact shard regions into scol
// (coalesced) counting degrees; (2) edge loop, 8 lanes per edge (j2=t&7):
// gather mu2[c*8+j2] from L2-resident mu_h, 2x atomicAdd into padded
// acc[196][17] fp32 (stride 17 spreads banks; uniform Poisson(32) degrees
// -> ~14%/wave same-node collisions); (3) normalize + LUT + coalesced NT
// store. 2 barriers, ~47KB LDS -> 3 blocks/CU (24 waves, +50% TLP on the
// latency-bound gather), low VGPR (no w[16]/rk[16] live arrays).
// ---------------------------------------------------------------------------
__global__ __launch_bounds__(512) void scatter_apply_kernel(
    const unsigned int* __restrict__ gcnt, const unsigned int* __restrict__ packed,
    const __half* __restrict__ mu_h, const float* __restrict__ lut,
    float* __restrict__ out) {
  __shared__ unsigned int scol[CAP_BIN];        // 32 KB compact (rl<<17|c) words
  __shared__ float acc[NPB * ACCW];             // 13.3 KB padded accumulators
  __shared__ int dcnt[NPB];
  __shared__ int scnt_s[NSH];

  int t = threadIdx.x;
  int bin = blockIdx.x;
  const unsigned int* pp = packed + (size_t)bin * CAP_BIN;

  for (int i = t; i < NPB * ACCW; i += 512) acc[i] = 0.0f;
  if (t < NPB) dcnt[t] = 0;
  if (t < NSH) scnt_s[t] = min((int)gcnt[bin * NSH + t], CAP_SH);
  __syncthreads();

  // per-thread shard prefix (8 broadcast LDS reads, no serial thread-0)
  int pfx[NSH + 1];
  pfx[0] = 0;
#pragma unroll
  for (int q = 0; q < NSH; ++q) pfx[q + 1] = pfx[q] + scnt_s[q];
  int cnt = pfx[NSH];

  // compact stage: word i = t*16 + k lives in shard i>>10 at offset i&1023;
  // valid iff offset < shard count. Writes to scol are coalesced per run.
  {
    const uint4* pp4 = (const uint4*)pp;
    uint4 a[4];
#pragma unroll
    for (int q = 0; q < 4; ++q) a[q] = pp4[t * 4 + q];
#pragma unroll
    for (int q = 0; q < 4; ++q) {
      unsigned int wq[4] = {a[q].x, a[q].y, a[q].z, a[q].w};
#pragma unroll
      for (int u = 0; u < 4; ++u) {
        int i = t * 16 + q * 4 + u;
        int sh = i >> 10;
        int off = i & (CAP_SH - 1);
        if (off < scnt_s[sh]) {
          unsigned int wv = wq[u];
          scol[pfx[sh] + off] = wv;
          atomicAdd(&dcnt[wv >> 17], 1);
        }
      }
    }
  }
  __syncthreads();

  // edge loop: 8 lanes per edge; lane j2 handles batch pair (2*j2, 2*j2+1)
  int j2 = t & 7;
  int es0 = t >> 3;
  const __half2* mu2 = (const __half2*)mu_h;   // [node][8] half2
  for (int i = es0; i < cnt; i += 64) {
    unsigned int wv = scol[i];
    int rl = (int)(wv >> 17);
    int c  = (int)(wv & 0x1FFFFu);
    float2 f = __half22float2(mu2[(size_t)c * 8 + j2]);
    atomicAdd(&acc[rl * ACCW + 2 * j2],     f.x);
    atomicAdd(&acc[rl * ACCW + 2 * j2 + 1], f.y);
  }
  __syncthreads();

  // tail: normalize + LUT + store; idx = j*NPB + nl -> 196-wide coalesced runs
  int binBase = bin * NPB;
  for (int idx = t; idx < BATCH * NPB; idx += 512) {
    int j = idx / NPB;                       // magic-mul
    int nl = idx - j * NPB;
    int node = binBase + nl;
    if (node < N_NODES) {
      float dinv = 1.0f / (float)max(dcnt[nl], 1);
      float x = acc[nl * ACCW + j] * dinv;
      float u = (x - LUT_LO) * LUT_SCALE;
      u = fminf(fmaxf(u, 0.0f), (float)LUT_SIZE - 0.001f);
      int ii = (int)u;
      float frac = u - (float)ii;
      float lo = lut[ii];
      float hi = lut[ii + 1];
      __builtin_nontemporal_store(fmaf(hi - lo, frac, lo),
                                  &out[(size_t)j * N_NODES + node]);
    }
  }
}

extern "C" void kernel_launch(void* const* d_in, const int* in_sizes, int n_in,
                              void* d_out, int out_size, void* d_ws, size_t ws_size,
                              hipStream_t stream) {
  const float* mu = (const float*)d_in[0];
  const int*   ei = (const int*)d_in[1];
  const float* W1 = (const float*)d_in[2];
  const float* b1 = (const float*)d_in[3];
  const float* W2 = (const float*)d_in[4];
  const float* b2 = (const float*)d_in[5];
  float* out = (float*)d_out;

  // ws: [mu_h 3.2MB][lut 32.8KB][gcnt 16KB][packed 16.8MB] ~ 20MB
  __half* mu_h = (__half*)d_ws;
  float* lut  = (float*)(mu_h + (size_t)N_NODES * BATCH);
  unsigned int* gcnt = (unsigned int*)(lut + LUT_SIZE + 1);
  unsigned int* packed = gcnt + NBINS * NSH;

  (void)hipMemsetAsync(gcnt, 0, NBINS * NSH * sizeof(unsigned int), stream);

  fused_part_prep_kernel<<<PBLKS + TBLKS + LBLKS, 512, 0, stream>>>(
      ei, gcnt, packed, mu, mu_h, W1, b1, W2, b2, lut);

  scatter_apply_kernel<<<NBINS, 512, 0, stream>>>(gcnt, packed, mu_h, lut, out);
}

// Round 10
// 126.813 us; speedup vs baseline: 2.9011x; 2.9011x over previous
//
#include <hip/hip_runtime.h>
#include <hip/hip_fp16.h>

#define N_NODES 100000
#define N_EDGES 3200000
#define BATCH   16
#define HIDDEN  64

#define NBINS   512
#define NPB     196      /* nodes per bin; 512*196 = 100352 >= N_NODES */
#define NSH     8        /* gcnt shards per bin (pblk & 7): 391/8 ~ 49 contenders */
#define CAP_SH  1024     /* words per shard region; mean 800, sigma 28 -> +8 sigma */
#define CAP_BIN 8192     /* NSH * CAP_SH */
#define EPB     8192     /* 16 edges/thread x 512 thr; 391 partition blocks */
#define MAXW    16       /* CAP_BIN / 512 */

#define PBLKS   391      /* partition blocks: 391*8192 >= 3.2M */
#define TBLKS   196      /* transpose blocks (512 thr): 196*512 >= 100000 */
#define LBLKS   17       /* lut blocks (512 thr): 17*512 >= 8193 */

#define LUT_SIZE  8192
#define LUT_LO    (-16.0f)
#define LUT_SCALE (LUT_SIZE / 32.0f)

typedef int v4i __attribute__((ext_vector_type(4)));
typedef unsigned int v4u __attribute__((ext_vector_type(4)));

// ---------------------------------------------------------------------------
// Kernel 1 — EXACT round-5 winner (124.4us). Round-8's LDS-fp32-atomic k2
// rewrite was falsified (272us, 1.76M LDS bank conflicts: per-address RMW
// serialization); sort-then-sum restored.
// Transpose+LUT blocks first (ids 0..212) overlapping partition blocks
// (ids 213..603). Partition: radix by dest bin (r/NPB), LDS atomic
// histogram+rank, shfl scan, place at prefix+rank, coalesced run copy-out;
// global reservation sharded 8 ways. Plain stores (L2 write-combines).
// gcnt is zeroed by hipMemsetAsync before this kernel.
// Packed word: (r_local << 17) | c  (8 + 17 = 25 bits).
// ---------------------------------------------------------------------------
__global__ __launch_bounds__(512) void fused_part_prep_kernel(
    const int* __restrict__ ei, unsigned int* __restrict__ gcnt,
    unsigned int* __restrict__ packed,
    const float* __restrict__ mu, __half* __restrict__ mu_h,
    const float* __restrict__ W1, const float* __restrict__ b1,
    const float* __restrict__ W2, const float* __restrict__ b2,
    float* __restrict__ lut) {
  __shared__ int aux[NBINS];               // 2 KB: cnt -> prefix
  __shared__ int dlt[NBINS];               // 2 KB: delta = shard base - prefix
  __shared__ int wsum[8];
  __shared__ unsigned int stag[EPB];       // 32 KB
  __shared__ unsigned short sbin[EPB];     // 16 KB

  int blk = blockIdx.x;
  int t = threadIdx.x;

  if (blk < TBLKS + LBLKS) {
    if (blk < TBLKS) {
      // ---- transpose (runs concurrently with partition blocks) ----
      int n = blk * 512 + t;
      if (n >= N_NODES) return;
      float4 o[4];
#pragma unroll
      for (int q = 0; q < 4; ++q) {
        o[q].x = mu[(q * 4 + 0) * N_NODES + n];
        o[q].y = mu[(q * 4 + 1) * N_NODES + n];
        o[q].z = mu[(q * 4 + 2) * N_NODES + n];
        o[q].w = mu[(q * 4 + 3) * N_NODES + n];
      }
      __half2 hh[8];
#pragma unroll
      for (int q = 0; q < 4; ++q) {
        hh[2 * q]     = __floats2half2_rn(o[q].x, o[q].y);
        hh[2 * q + 1] = __floats2half2_rn(o[q].z, o[q].w);
      }
      int4 w0 = make_int4(*(int*)&hh[0], *(int*)&hh[1], *(int*)&hh[2], *(int*)&hh[3]);
      int4 w1 = make_int4(*(int*)&hh[4], *(int*)&hh[5], *(int*)&hh[6], *(int*)&hh[7]);
      int4* dst = (int4*)(mu_h + (size_t)n * BATCH);
      dst[0] = w0;
      dst[1] = w1;
    } else {
      // ---- LUT ----
      int i = (blk - TBLKS) * 512 + t;
      if (i > LUT_SIZE) return;
      float x = LUT_LO + (float)i / LUT_SCALE;
      float acc = b2[0];
      for (int h = 0; h < HIDDEN; ++h) {
        float z = fmaf(x, W1[h], b1[h]);
        float g = 0.5f * z * (1.0f + erff(z * 0.70710678118654752f));
        acc = fmaf(g, W2[h], acc);
      }
      lut[i] = acc;
    }
    return;
  }

  // ---- partition ----
  int pblk = blk - (TBLKS + LBLKS);
  int base = pblk * EPB;
  int nvalid = min(EPB, N_EDGES - base);
  int sh = pblk & (NSH - 1);
  aux[t] = 0;
  __syncthreads();

  unsigned int pk[16];
  int bn[16];
  int rk[16];
  if (t * 16 + 16 <= nvalid) {
    const v4i* rp = (const v4i*)(ei + base + t * 16);          // 64B aligned
    const v4i* cp = (const v4i*)(ei + N_EDGES + base + t * 16);
    v4i rr[4], cc[4];
#pragma unroll
    for (int q = 0; q < 4; ++q) {
      rr[q] = rp[q];
      cc[q] = cp[q];
    }
#pragma unroll
    for (int q = 0; q < 4; ++q) {
#pragma unroll
      for (int u = 0; u < 4; ++u) {
        int k = q * 4 + u;
        int r = rr[q][u];
        int c = cc[q][u];
        int b = r / NPB;                    // magic-mul
        int rl = r - b * NPB;
        pk[k] = ((unsigned int)rl << 17) | (unsigned int)c;
        bn[k] = b;
      }
    }
#pragma unroll
    for (int k = 0; k < 16; ++k) rk[k] = atomicAdd(&aux[bn[k]], 1);
  } else {
#pragma unroll
    for (int k = 0; k < 16; ++k) {
      int e = t * 16 + k;
      if (e < nvalid) {
        int r = ei[base + e];
        int c = ei[N_EDGES + base + e];
        int b = r / NPB;
        int rl = r - b * NPB;
        pk[k] = ((unsigned int)rl << 17) | (unsigned int)c;
        bn[k] = b;
        rk[k] = atomicAdd(&aux[b], 1);
      } else {
        bn[k] = -1;
      }
    }
  }
  __syncthreads();

  // shfl scan over 512 bins (one per thread); aux: cnt -> prefix
  int lane = t & 63;
  int wid = t >> 6;
  int v = aux[t];

  // reserve sharded global space early (latency hidden behind scan);
  // per-address contention ~49 blocks instead of 391
  unsigned int gb = v ? atomicAdd(&gcnt[t * NSH + sh], (unsigned int)v) : 0u;

  int sv = v;
#pragma unroll
  for (int d = 1; d < 64; d <<= 1) {
    int n = __shfl_up(sv, d, 64);
    if (lane >= d) sv += n;
  }
  if (lane == 63) wsum[wid] = sv;
  __syncthreads();
  if (t < 8) {
    int s = wsum[t];
#pragma unroll
    for (int d = 1; d < 8; d <<= 1) {
      int n = __shfl_up(s, d, 8);
      if (t >= d) s += n;
    }
    wsum[t] = s;
  }
  __syncthreads();
  int pexcl = sv + (wid ? wsum[wid - 1] : 0) - v;
  aux[t] = pexcl;                              // prefix for the place pass
  dlt[t] = (int)(sh * CAP_SH + gb) - pexcl;    // delta for the copy-out pass
  __syncthreads();

  // place at prefix+rank (no atomics)
#pragma unroll
  for (int k = 0; k < 16; ++k) {
    if (bn[k] >= 0) {
      int p = aux[bn[k]] + rk[k];
      stag[p] = pk[k];
      sbin[p] = (unsigned short)bn[k];
    }
  }
  __syncthreads();

  // coalesced copy-out: pos = i + delta[bin]; drop past own shard region.
  // Plain stores: write-combine in L2, full-line writeback at kernel end.
  unsigned int lim = (unsigned int)((sh + 1) * CAP_SH);
  for (int i = t; i < nvalid; i += 512) {
    int b = sbin[i];
    unsigned int pos = (unsigned int)(i + dlt[b]);
    if (pos < lim)
      packed[(size_t)b * CAP_BIN + pos] = stag[i];
  }
}

// ---------------------------------------------------------------------------
// Kernel 2 — round-5 sort-then-sum, ONE delta: the 16.8MB packed stream is
// read ONCE, but with full L2 allocation it continuously evicts the 3.2MB
// mu_h gather working set (barely fits a 4MB per-XCD L2 alone), turning
// ~200cy L2-hit gathers into ~450cy L3 trips on k2's serial tail. NT hints
// on the 4x packed vector loads (evict-first in L2) protect mu_h residency.
// (Round-9 compile fix: NT load via ext_vector_type v4u, not HIP's uint4
// struct.) Everything else identical to the 124.4us config.
// ---------------------------------------------------------------------------
__global__ __launch_bounds__(512) void scatter_apply_kernel(
    const unsigned int* __restrict__ gcnt, const unsigned int* __restrict__ packed,
    const __half* __restrict__ mu_h, const float* __restrict__ lut,
    float* __restrict__ out) {
  __shared__ unsigned int scol[CAP_BIN];    // 32 KB node-sorted cols
  __shared__ int dcnt[NPB];
  __shared__ int ebase[NPB];
  __shared__ int wpart[4];
  __shared__ int scnt_s[NSH];

  int t = threadIdx.x;
  int bin = blockIdx.x;

  const unsigned int* pp = packed + (size_t)bin * CAP_BIN;

  if (t < NPB) dcnt[t] = 0;
  if (t < NSH) scnt_s[t] = min((int)gcnt[bin * NSH + t], CAP_SH);
  __syncthreads();

  // branch-free loads: 4x dwordx4 NON-TEMPORAL (single-use stream; keep L2
  // for mu_h), all 16 words issued before any use. word k at t*16 + k.
  unsigned int w[MAXW];
  {
    const v4u* pp4 = (const v4u*)pp;
#pragma unroll
    for (int q = 0; q < 4; ++q) {
      v4u a = __builtin_nontemporal_load(&pp4[t * 4 + q]);
      w[q * 4 + 0] = a.x;
      w[q * 4 + 1] = a.y;
      w[q * 4 + 2] = a.z;
      w[q * 4 + 3] = a.w;
    }
  }

  int rk[MAXW];
#pragma unroll
  for (int k = 0; k < MAXW; ++k) {
    int i = t * 16 + k;
    int off = i & (CAP_SH - 1);            // offset within shard i>>10
    rk[k] = (off < scnt_s[i >> 10]) ? atomicAdd(&dcnt[w[k] >> 17], 1) : 0;
  }
  __syncthreads();

  // shfl scan over NPB=196 counters (4 waves, padded to 256)
  int v = 0, sv = 0;
  if (t < 256) {
    v = (t < NPB) ? dcnt[t] : 0;
    int lane = t & 63;
    sv = v;
#pragma unroll
    for (int d = 1; d < 64; d <<= 1) {
      int n = __shfl_up(sv, d, 64);
      if (lane >= d) sv += n;
    }
    if (lane == 63) wpart[t >> 6] = sv;
  }
  __syncthreads();
  if (t < 256) {
    int wid = t >> 6;
    int off = 0;
#pragma unroll
    for (int q = 0; q < 3; ++q)
      if (wid > q) off += wpart[q];
    if (t < NPB) ebase[t] = sv + off - v;
  }
  __syncthreads();

  // place node-sorted cols (no atomics)
#pragma unroll
  for (int k = 0; k < MAXW; ++k) {
    int i = t * 16 + k;
    int off = i & (CAP_SH - 1);
    if (off < scnt_s[i >> 10]) {
      int rl = (int)(w[k] >> 17);
      scol[ebase[rl] + rk[k]] = w[k] & 0x1FFFFu;
    }
  }
  __syncthreads();

  // gather + register-accumulate + normalize + LUT + store
  const __half2* mu2 = (const __half2*)mu_h;   // [node][8] half2
  int j2 = t & 7;                              // batch pair 0..7
  int nsl = t >> 3;                            // node slot 0..63
  int binBase = bin * NPB;

#pragma unroll
  for (int pass = 0; pass < 4; ++pass) {
    int nl = pass * 64 + nsl;
    if (nl < NPB) {
      int node = binBase + nl;
      if (node < N_NODES) {
        int s = ebase[nl];
        int e = s + dcnt[nl];
        float2 a0 = {0.f, 0.f}, a1 = {0.f, 0.f};
        float2 a2 = {0.f, 0.f}, a3 = {0.f, 0.f};
        int i = s;
        for (; i + 8 <= e; i += 8) {
          int c0 = (int)scol[i];
          int c1 = (int)scol[i + 1];
          int c2 = (int)scol[i + 2];
          int c3 = (int)scol[i + 3];
          int c4 = (int)scol[i + 4];
          int c5 = (int)scol[i + 5];
          int c6 = (int)scol[i + 6];
          int c7 = (int)scol[i + 7];
          __half2 v0 = mu2[(size_t)c0 * 8 + j2];   // 8 independent gathers
          __half2 v1 = mu2[(size_t)c1 * 8 + j2];
          __half2 v2 = mu2[(size_t)c2 * 8 + j2];
          __half2 v3 = mu2[(size_t)c3 * 8 + j2];
          __half2 v4 = mu2[(size_t)c4 * 8 + j2];
          __half2 v5 = mu2[(size_t)c5 * 8 + j2];
          __half2 v6 = mu2[(size_t)c6 * 8 + j2];
          __half2 v7 = mu2[(size_t)c7 * 8 + j2];
          float2 f0 = __half22float2(v0);
          float2 f1 = __half22float2(v1);
          float2 f2 = __half22float2(v2);
          float2 f3 = __half22float2(v3);
          float2 f4 = __half22float2(v4);
          float2 f5 = __half22float2(v5);
          float2 f6 = __half22float2(v6);
          float2 f7 = __half22float2(v7);
          a0.x += f0.x + f4.x; a0.y += f0.y + f4.y;
          a1.x += f1.x + f5.x; a1.y += f1.y + f5.y;
          a2.x += f2.x + f6.x; a2.y += f2.y + f6.y;
          a3.x += f3.x + f7.x; a3.y += f3.y + f7.y;
        }
        for (; i + 4 <= e; i += 4) {
          int c0 = (int)scol[i];
          int c1 = (int)scol[i + 1];
          int c2 = (int)scol[i + 2];
          int c3 = (int)scol[i + 3];
          __half2 v0 = mu2[(size_t)c0 * 8 + j2];
          __half2 v1 = mu2[(size_t)c1 * 8 + j2];
          __half2 v2 = mu2[(size_t)c2 * 8 + j2];
          __half2 v3 = mu2[(size_t)c3 * 8 + j2];
          float2 f0 = __half22float2(v0);
          float2 f1 = __half22float2(v1);
          float2 f2 = __half22float2(v2);
          float2 f3 = __half22float2(v3);
          a0.x += f0.x; a0.y += f0.y;
          a1.x += f1.x; a1.y += f1.y;
          a2.x += f2.x; a2.y += f2.y;
          a3.x += f3.x; a3.y += f3.y;
        }
        for (; i < e; ++i) {
          float2 f = __half22float2(mu2[(size_t)scol[i] * 8 + j2]);
          a0.x += f.x; a0.y += f.y;
        }
        float sx = (a0.x + a1.x) + (a2.x + a3.x);
        float sy = (a0.y + a1.y) + (a2.y + a3.y);
        float dinv = 1.0f / (float)max(e - s, 1);

        float xs[2] = {sx * dinv, sy * dinv};
#pragma unroll
        for (int q = 0; q < 2; ++q) {
          float u = (xs[q] - LUT_LO) * LUT_SCALE;
          u = fminf(fmaxf(u, 0.0f), (float)LUT_SIZE - 0.001f);
          int ii = (int)u;
          float frac = u - (float)ii;
          float lo = lut[ii];
          float hi = lut[ii + 1];
          __builtin_nontemporal_store(fmaf(hi - lo, frac, lo),
                                      &out[(size_t)(2 * j2 + q) * N_NODES + node]);
        }
      }
    }
  }
}

extern "C" void kernel_launch(void* const* d_in, const int* in_sizes, int n_in,
                              void* d_out, int out_size, void* d_ws, size_t ws_size,
                              hipStream_t stream) {
  const float* mu = (const float*)d_in[0];
  const int*   ei = (const int*)d_in[1];
  const float* W1 = (const float*)d_in[2];
  const float* b1 = (const float*)d_in[3];
  const float* W2 = (const float*)d_in[4];
  const float* b2 = (const float*)d_in[5];
  float* out = (float*)d_out;

  // ws: [mu_h 3.2MB][lut 32.8KB][gcnt 16KB][packed 16.8MB] ~ 20MB
  __half* mu_h = (__half*)d_ws;
  float* lut  = (float*)(mu_h + (size_t)N_NODES * BATCH);
  unsigned int* gcnt = (unsigned int*)(lut + LUT_SIZE + 1);
  unsigned int* packed = gcnt + NBINS * NSH;

  (void)hipMemsetAsync(gcnt, 0, NBINS * NSH * sizeof(unsigned int), stream);

  fused_part_prep_kernel<<<PBLKS + TBLKS + LBLKS, 512, 0, stream>>>(
      ei, gcnt, packed, mu, mu_h, W1, b1, W2, b2, lut);

  scatter_apply_kernel<<<NBINS, 512, 0, stream>>>(gcnt, packed, mu_h, lut, out);
}

// Round 11
// 124.362 us; speedup vs baseline: 2.9583x; 1.0197x over previous
//
#include <hip/hip_runtime.h>
#include <hip/hip_fp16.h>

#define N_NODES 100000
#define N_EDGES 3200000
#define BATCH   16
#define HIDDEN  64

#define NBINS   512
#define NPB     196      /* nodes per bin; 512*196 = 100352 >= N_NODES */
#define NSH     8        /* gcnt shards per bin (pblk & 7): 391/8 ~ 49 contenders */
#define CAP_SH  1024     /* words per shard region; mean 800, sigma 28 -> +8 sigma */
#define CAP_BIN 8192     /* NSH * CAP_SH */
#define EPB     8192     /* 16 edges/thread x 512 thr; 391 partition blocks */
#define MAXW    16       /* CAP_BIN / 512 */

#define PBLKS   391      /* partition blocks: 391*8192 >= 3.2M */
#define TBLKS   196      /* transpose blocks (512 thr): 196*512 >= 100000 */
#define LBLKS   17       /* lut blocks (512 thr): 17*512 >= 8193 */

#define LUT_SIZE  8192
#define LUT_LO    (-16.0f)
#define LUT_SCALE (LUT_SIZE / 32.0f)

typedef int v4i __attribute__((ext_vector_type(4)));

// ---------------------------------------------------------------------------
// Kernel 1 — round-5 winner (124.4us) + ROUND 11 delta: __launch_bounds__
// (512,6) forces VGPR<=85 so 3 blocks/CU fit (LDS 52KB x3 < 160KB), raising
// residency 16 -> 24 waves/CU. Evidence: k1 ~48us vs ~8us BW floor with
// VALUBusy<5%, HBM~15% (round-1 family) = latency-bound, under-occupied;
// live arrays pk/bn/rk (48 VGPR) likely pushed allocation past the
// 2-block cliff. If the compiler spills instead, this regresses -> revert.
// Transpose+LUT blocks first (ids 0..212) overlapping partition blocks.
// Partition: radix by dest bin (r/NPB), LDS atomic histogram+rank, shfl
// scan, place at prefix+rank, coalesced run copy-out; global reservation
// sharded 8 ways. Plain stores (L2 write-combines). Round-10's NT packed
// loads reverted (126.8 vs 124.4 -> mu_h-residency theory falsified).
// gcnt is zeroed by hipMemsetAsync before this kernel.
// Packed word: (r_local << 17) | c  (8 + 17 = 25 bits).
// ---------------------------------------------------------------------------
__global__ __launch_bounds__(512, 6) void fused_part_prep_kernel(
    const int* __restrict__ ei, unsigned int* __restrict__ gcnt,
    unsigned int* __restrict__ packed,
    const float* __restrict__ mu, __half* __restrict__ mu_h,
    const float* __restrict__ W1, const float* __restrict__ b1,
    const float* __restrict__ W2, const float* __restrict__ b2,
    float* __restrict__ lut) {
  __shared__ int aux[NBINS];               // 2 KB: cnt -> prefix
  __shared__ int dlt[NBINS];               // 2 KB: delta = shard base - prefix
  __shared__ int wsum[8];
  __shared__ unsigned int stag[EPB];       // 32 KB
  __shared__ unsigned short sbin[EPB];     // 16 KB

  int blk = blockIdx.x;
  int t = threadIdx.x;

  if (blk < TBLKS + LBLKS) {
    if (blk < TBLKS) {
      // ---- transpose (runs concurrently with partition blocks) ----
      int n = blk * 512 + t;
      if (n >= N_NODES) return;
      float4 o[4];
#pragma unroll
      for (int q = 0; q < 4; ++q) {
        o[q].x = mu[(q * 4 + 0) * N_NODES + n];
        o[q].y = mu[(q * 4 + 1) * N_NODES + n];
        o[q].z = mu[(q * 4 + 2) * N_NODES + n];
        o[q].w = mu[(q * 4 + 3) * N_NODES + n];
      }
      __half2 hh[8];
#pragma unroll
      for (int q = 0; q < 4; ++q) {
        hh[2 * q]     = __floats2half2_rn(o[q].x, o[q].y);
        hh[2 * q + 1] = __floats2half2_rn(o[q].z, o[q].w);
      }
      int4 w0 = make_int4(*(int*)&hh[0], *(int*)&hh[1], *(int*)&hh[2], *(int*)&hh[3]);
      int4 w1 = make_int4(*(int*)&hh[4], *(int*)&hh[5], *(int*)&hh[6], *(int*)&hh[7]);
      int4* dst = (int4*)(mu_h + (size_t)n * BATCH);
      dst[0] = w0;
      dst[1] = w1;
    } else {
      // ---- LUT ----
      int i = (blk - TBLKS) * 512 + t;
      if (i > LUT_SIZE) return;
      float x = LUT_LO + (float)i / LUT_SCALE;
      float acc = b2[0];
      for (int h = 0; h < HIDDEN; ++h) {
        float z = fmaf(x, W1[h], b1[h]);
        float g = 0.5f * z * (1.0f + erff(z * 0.70710678118654752f));
        acc = fmaf(g, W2[h], acc);
      }
      lut[i] = acc;
    }
    return;
  }

  // ---- partition ----
  int pblk = blk - (TBLKS + LBLKS);
  int base = pblk * EPB;
  int nvalid = min(EPB, N_EDGES - base);
  int sh = pblk & (NSH - 1);
  aux[t] = 0;
  __syncthreads();

  unsigned int pk[16];
  int bn[16];
  int rk[16];
  if (t * 16 + 16 <= nvalid) {
    const v4i* rp = (const v4i*)(ei + base + t * 16);          // 64B aligned
    const v4i* cp = (const v4i*)(ei + N_EDGES + base + t * 16);
    v4i rr[4], cc[4];
#pragma unroll
    for (int q = 0; q < 4; ++q) {
      rr[q] = rp[q];
      cc[q] = cp[q];
    }
#pragma unroll
    for (int q = 0; q < 4; ++q) {
#pragma unroll
      for (int u = 0; u < 4; ++u) {
        int k = q * 4 + u;
        int r = rr[q][u];
        int c = cc[q][u];
        int b = r / NPB;                    // magic-mul
        int rl = r - b * NPB;
        pk[k] = ((unsigned int)rl << 17) | (unsigned int)c;
        bn[k] = b;
      }
    }
#pragma unroll
    for (int k = 0; k < 16; ++k) rk[k] = atomicAdd(&aux[bn[k]], 1);
  } else {
#pragma unroll
    for (int k = 0; k < 16; ++k) {
      int e = t * 16 + k;
      if (e < nvalid) {
        int r = ei[base + e];
        int c = ei[N_EDGES + base + e];
        int b = r / NPB;
        int rl = r - b * NPB;
        pk[k] = ((unsigned int)rl << 17) | (unsigned int)c;
        bn[k] = b;
        rk[k] = atomicAdd(&aux[b], 1);
      } else {
        bn[k] = -1;
      }
    }
  }
  __syncthreads();

  // shfl scan over 512 bins (one per thread); aux: cnt -> prefix
  int lane = t & 63;
  int wid = t >> 6;
  int v = aux[t];

  // reserve sharded global space early (latency hidden behind scan);
  // per-address contention ~49 blocks instead of 391
  unsigned int gb = v ? atomicAdd(&gcnt[t * NSH + sh], (unsigned int)v) : 0u;

  int sv = v;
#pragma unroll
  for (int d = 1; d < 64; d <<= 1) {
    int n = __shfl_up(sv, d, 64);
    if (lane >= d) sv += n;
  }
  if (lane == 63) wsum[wid] = sv;
  __syncthreads();
  if (t < 8) {
    int s = wsum[t];
#pragma unroll
    for (int d = 1; d < 8; d <<= 1) {
      int n = __shfl_up(s, d, 8);
      if (t >= d) s += n;
    }
    wsum[t] = s;
  }
  __syncthreads();
  int pexcl = sv + (wid ? wsum[wid - 1] : 0) - v;
  aux[t] = pexcl;                              // prefix for the place pass
  dlt[t] = (int)(sh * CAP_SH + gb) - pexcl;    // delta for the copy-out pass
  __syncthreads();

  // place at prefix+rank (no atomics)
#pragma unroll
  for (int k = 0; k < 16; ++k) {
    if (bn[k] >= 0) {
      int p = aux[bn[k]] + rk[k];
      stag[p] = pk[k];
      sbin[p] = (unsigned short)bn[k];
    }
  }
  __syncthreads();

  // coalesced copy-out: pos = i + delta[bin]; drop past own shard region.
  // Plain stores: write-combine in L2, full-line writeback at kernel end.
  unsigned int lim = (unsigned int)((sh + 1) * CAP_SH);
  for (int i = t; i < nvalid; i += 512) {
    int b = sbin[i];
    unsigned int pos = (unsigned int)(i + dlt[b]);
    if (pos < lim)
      packed[(size_t)b * CAP_BIN + pos] = stag[i];
  }
}

// ---------------------------------------------------------------------------
// Kernel 2 — round-5 sort-then-sum (plain packed loads; round-10's NT hint
// reverted) + __launch_bounds__(512,6): VGPR<=85 -> 3 blocks/CU (LDS 33KB
// x3 < 160KB), 24 waves/CU on the latency-bound gather phase.
// ---------------------------------------------------------------------------
__global__ __launch_bounds__(512, 6) void scatter_apply_kernel(
    const unsigned int* __restrict__ gcnt, const unsigned int* __restrict__ packed,
    const __half* __restrict__ mu_h, const float* __restrict__ lut,
    float* __restrict__ out) {
  __shared__ unsigned int scol[CAP_BIN];    // 32 KB node-sorted cols
  __shared__ int dcnt[NPB];
  __shared__ int ebase[NPB];
  __shared__ int wpart[4];
  __shared__ int scnt_s[NSH];

  int t = threadIdx.x;
  int bin = blockIdx.x;

  const unsigned int* pp = packed + (size_t)bin * CAP_BIN;

  if (t < NPB) dcnt[t] = 0;
  if (t < NSH) scnt_s[t] = min((int)gcnt[bin * NSH + t], CAP_SH);
  __syncthreads();

  // branch-free loads: 4x dwordx4, all 16 words issued before any use.
  // word k lives at global index t*16 + k.
  unsigned int w[MAXW];
  {
    const uint4* pp4 = (const uint4*)pp;
#pragma unroll
    for (int q = 0; q < 4; ++q) {
      uint4 a = pp4[t * 4 + q];
      w[q * 4 + 0] = a.x;
      w[q * 4 + 1] = a.y;
      w[q * 4 + 2] = a.z;
      w[q * 4 + 3] = a.w;
    }
  }

  int rk[MAXW];
#pragma unroll
  for (int k = 0; k < MAXW; ++k) {
    int i = t * 16 + k;
    int off = i & (CAP_SH - 1);            // offset within shard i>>10
    rk[k] = (off < scnt_s[i >> 10]) ? atomicAdd(&dcnt[w[k] >> 17], 1) : 0;
  }
  __syncthreads();

  // shfl scan over NPB=196 counters (4 waves, padded to 256)
  int v = 0, sv = 0;
  if (t < 256) {
    v = (t < NPB) ? dcnt[t] : 0;
    int lane = t & 63;
    sv = v;
#pragma unroll
    for (int d = 1; d < 64; d <<= 1) {
      int n = __shfl_up(sv, d, 64);
      if (lane >= d) sv += n;
    }
    if (lane == 63) wpart[t >> 6] = sv;
  }
  __syncthreads();
  if (t < 256) {
    int wid = t >> 6;
    int off = 0;
#pragma unroll
    for (int q = 0; q < 3; ++q)
      if (wid > q) off += wpart[q];
    if (t < NPB) ebase[t] = sv + off - v;
  }
  __syncthreads();

  // place node-sorted cols (no atomics)
#pragma unroll
  for (int k = 0; k < MAXW; ++k) {
    int i = t * 16 + k;
    int off = i & (CAP_SH - 1);
    if (off < scnt_s[i >> 10]) {
      int rl = (int)(w[k] >> 17);
      scol[ebase[rl] + rk[k]] = w[k] & 0x1FFFFu;
    }
  }
  __syncthreads();

  // gather + register-accumulate + normalize + LUT + store
  const __half2* mu2 = (const __half2*)mu_h;   // [node][8] half2
  int j2 = t & 7;                              // batch pair 0..7
  int nsl = t >> 3;                            // node slot 0..63
  int binBase = bin * NPB;

#pragma unroll
  for (int pass = 0; pass < 4; ++pass) {
    int nl = pass * 64 + nsl;
    if (nl < NPB) {
      int node = binBase + nl;
      if (node < N_NODES) {
        int s = ebase[nl];
        int e = s + dcnt[nl];
        float2 a0 = {0.f, 0.f}, a1 = {0.f, 0.f};
        float2 a2 = {0.f, 0.f}, a3 = {0.f, 0.f};
        int i = s;
        for (; i + 8 <= e; i += 8) {
          int c0 = (int)scol[i];
          int c1 = (int)scol[i + 1];
          int c2 = (int)scol[i + 2];
          int c3 = (int)scol[i + 3];
          int c4 = (int)scol[i + 4];
          int c5 = (int)scol[i + 5];
          int c6 = (int)scol[i + 6];
          int c7 = (int)scol[i + 7];
          __half2 v0 = mu2[(size_t)c0 * 8 + j2];   // 8 independent gathers
          __half2 v1 = mu2[(size_t)c1 * 8 + j2];
          __half2 v2 = mu2[(size_t)c2 * 8 + j2];
          __half2 v3 = mu2[(size_t)c3 * 8 + j2];
          __half2 v4 = mu2[(size_t)c4 * 8 + j2];
          __half2 v5 = mu2[(size_t)c5 * 8 + j2];
          __half2 v6 = mu2[(size_t)c6 * 8 + j2];
          __half2 v7 = mu2[(size_t)c7 * 8 + j2];
          float2 f0 = __half22float2(v0);
          float2 f1 = __half22float2(v1);
          float2 f2 = __half22float2(v2);
          float2 f3 = __half22float2(v3);
          float2 f4 = __half22float2(v4);
          float2 f5 = __half22float2(v5);
          float2 f6 = __half22float2(v6);
          float2 f7 = __half22float2(v7);
          a0.x += f0.x + f4.x; a0.y += f0.y + f4.y;
          a1.x += f1.x + f5.x; a1.y += f1.y + f5.y;
          a2.x += f2.x + f6.x; a2.y += f2.y + f6.y;
          a3.x += f3.x + f7.x; a3.y += f3.y + f7.y;
        }
        for (; i + 4 <= e; i += 4) {
          int c0 = (int)scol[i];
          int c1 = (int)scol[i + 1];
          int c2 = (int)scol[i + 2];
          int c3 = (int)scol[i + 3];
          __half2 v0 = mu2[(size_t)c0 * 8 + j2];
          __half2 v1 = mu2[(size_t)c1 * 8 + j2];
          __half2 v2 = mu2[(size_t)c2 * 8 + j2];
          __half2 v3 = mu2[(size_t)c3 * 8 + j2];
          float2 f0 = __half22float2(v0);
          float2 f1 = __half22float2(v1);
          float2 f2 = __half22float2(v2);
          float2 f3 = __half22float2(v3);
          a0.x += f0.x; a0.y += f0.y;
          a1.x += f1.x; a1.y += f1.y;
          a2.x += f2.x; a2.y += f2.y;
          a3.x += f3.x; a3.y += f3.y;
        }
        for (; i < e; ++i) {
          float2 f = __half22float2(mu2[(size_t)scol[i] * 8 + j2]);
          a0.x += f.x; a0.y += f.y;
        }
        float sx = (a0.x + a1.x) + (a2.x + a3.x);
        float sy = (a0.y + a1.y) + (a2.y + a3.y);
        float dinv = 1.0f / (float)max(e - s, 1);

        float xs[2] = {sx * dinv, sy * dinv};
#pragma unroll
        for (int q = 0; q < 2; ++q) {
          float u = (xs[q] - LUT_LO) * LUT_SCALE;
          u = fminf(fmaxf(u, 0.0f), (float)LUT_SIZE - 0.001f);
          int ii = (int)u;
          float frac = u - (float)ii;
          float lo = lut[ii];
          float hi = lut[ii + 1];
          __builtin_nontemporal_store(fmaf(hi - lo, frac, lo),
                                      &out[(size_t)(2 * j2 + q) * N_NODES + node]);
        }
      }
    }
  }
}

extern "C" void kernel_launch(void* const* d_in, const int* in_sizes, int n_in,
                              void* d_out, int out_size, void* d_ws, size_t ws_size,
                              hipStream_t stream) {
  const float* mu = (const float*)d_in[0];
  const int*   ei = (const int*)d_in[1];
  const float* W1 = (const float*)d_in[2];
  const float* b1 = (const float*)d_in[3];
  const float* W2 = (const float*)d_in[4];
  const float* b2 = (const float*)d_in[5];
  float* out = (float*)d_out;

  // ws: [mu_h 3.2MB][lut 32.8KB][gcnt 16KB][packed 16.8MB] ~ 20MB
  __half* mu_h = (__half*)d_ws;
  float* lut  = (float*)(mu_h + (size_t)N_NODES * BATCH);
  unsigned int* gcnt = (unsigned int*)(lut + LUT_SIZE + 1);
  unsigned int* packed = gcnt + NBINS * NSH;

  (void)hipMemsetAsync(gcnt, 0, NBINS * NSH * sizeof(unsigned int), stream);

  fused_part_prep_kernel<<<PBLKS + TBLKS + LBLKS, 512, 0, stream>>>(
      ei, gcnt, packed, mu, mu_h, W1, b1, W2, b2, lut);

  scatter_apply_kernel<<<NBINS, 512, 0, stream>>>(gcnt, packed, mu_h, lut, out);
}